// Round 8
// baseline (628.857 us; speedup 1.0000x reference)
//
#include <hip/hip_runtime.h>

// LIF scan: B=16, S=256, H=128, N=64. T = S*H = 32768 sequential steps per
// (b,n) chain; 1024 chains. Bit-exactness with the numpy fp32 sequential
// reference required -> the add chain cannot be reassociated. Chain form
// (proven bit-exact R1..R7, absmax=0):
//     s' = prev ? x : fl(s + x);  prev' = s' > th
//
// R7 post-mortem: 4-buffer register pipeline defeated by the allocator
// (VGPR=136, not 256+): loads rotated back next to consumes -> one exposed
// HBM latency (~1000 cyc) per 64-step chunk = 24.3 cyc/step. Also: every
// dense-write kernel so far caps at ~1 TB/s -> pass2 under test this round
// (plain stores, b128 LDS transpose).
//
// R8 pass1: producer/consumer waves (128 threads).
//   wave 0 (consumer): chains only. Hot loop = ds_read_b128 (broadcast) +
//     3 VALU/step. NO vm ops -> barrier drains are free for it. Checkpoints
//     go to an LDS mailbox.
//   wave 1 (producer): global->LDS x-ring (4 x 1 KB granule slots, loads
//     issued one full granule ahead in a register) + drains the checkpoint
//     mailbox to d_ws with coalesced global stores. Its ~1000 cyc/granule
//     of latency hides under wave 0's ~2600 cyc/granule of compute.
//   One barrier per 256 steps (R4 failed at per-step coupling; 100x coarser).
// R8 pass2: replay per (b,row) as before, but LDS transposed ovt[n][h]
//   (16B-aligned rows -> ds_write_b128/ds_read_b128) and PLAIN stores (no nt).

namespace {
constexpr int kB = 16;
constexpr int kS = 256;
constexpr int kH = 128;
constexpr int kN = 64;
constexpr int kT = kS * kH;                 // 32768
constexpr long kPerB = (long)kS * kN * kH;  // 2,097,152 per batch per tensor
constexpr size_t kWsS = (size_t)kB * kS * kN * sizeof(float);          // 1 MB
constexpr size_t kWsM = (size_t)kB * kS * sizeof(unsigned long long);  // 32 KB
}

typedef float v4f __attribute__((ext_vector_type(4)));

// Opaque VGPR zero (R6-proven): defeats uniform-scalarization so broadcast
// x loads use the vector path (vmcnt) instead of SMEM s_loads (lgkmcnt).
__device__ __forceinline__ int opaque_vgpr_zero() {
  int z;
  asm volatile("v_mov_b32 %0, 0" : "=v"(z));
  return z;
}

// ---------------------------------------------------------------------------
// Pass 1: sequential chains, producer/consumer. block = batch (16 blocks,
// 128 threads). Granule = 1 KB of x = 256 steps = 2 S-rows; 128 granules.
// ---------------------------------------------------------------------------
__global__ __launch_bounds__(128, 1) void lif_pass1_kernel(
    const float* __restrict__ x, const float* __restrict__ thresh,
    const float* __restrict__ acc0, float* __restrict__ ckpt_s,
    unsigned long long* __restrict__ ckpt_m) {
  const int b = blockIdx.x;
  const int tid = threadIdx.x;
  const int wave = tid >> 6;
  const int lane = tid & 63;

  __shared__ alignas(16) float ring[4][256];      // 4 granule slots, 4 KB
  __shared__ alignas(16) float mail_s[2][2][64];  // [parity][row-of-2][lane]
  __shared__ unsigned long long mail_m[2][2];     // entering-prev ballots

  const v4f* __restrict__ xb4 = (const v4f*)(x + (long)b * kT);

  if (wave == 0) {
    // ---------------- consumer: the chains (no vm ops) ----------------
    const float th = thresh[lane];
    float s = acc0[b * kN + lane];
    bool prev = false;
    __syncthreads();  // pairs with producer prologue fill
    for (int k = 0; k < 128; ++k) {
      const float* base = ring[k & 3];
      // checkpoint: state entering row 2k -> mailbox (parity k&1)
      mail_s[k & 1][0][lane] = s;
      {
        const unsigned long long m = __ballot(prev);
        if (lane == 0) mail_m[k & 1][0] = m;
      }
#pragma unroll
      for (int q = 0; q < 32; ++q) {  // row 2k: 128 steps
        const v4f xq = *(const v4f*)(base + q * 4);  // ds_read_b128 broadcast
#pragma unroll
        for (int j = 0; j < 4; ++j) {
          const float xt = xq[j];
          const float u = s + xt;  // dep-chain op 1
          s = prev ? xt : u;       // dep-chain op 2
          prev = s > th;           // off-chain
        }
      }
      // checkpoint: state entering row 2k+1
      mail_s[k & 1][1][lane] = s;
      {
        const unsigned long long m = __ballot(prev);
        if (lane == 0) mail_m[k & 1][1] = m;
      }
#pragma unroll
      for (int q = 32; q < 64; ++q) {  // row 2k+1: 128 steps
        const v4f xq = *(const v4f*)(base + q * 4);
#pragma unroll
        for (int j = 0; j < 4; ++j) {
          const float xt = xq[j];
          const float u = s + xt;
          s = prev ? xt : u;
          prev = s > th;
        }
      }
      __syncthreads();  // granule boundary
    }
  } else {
    // ------------- producer: x staging + checkpoint flushing -------------
    float* __restrict__ cs = ckpt_s + (long)b * kS * kN;
    unsigned long long* __restrict__ cm = ckpt_m + (long)b * kS;

    // prologue: fill slots 0,1; preload granule 2 into a register
    v4f vbuf;
    {
      const v4f v0 = xb4[0 * 64 + lane];
      const v4f v1 = xb4[1 * 64 + lane];
      *(v4f*)&ring[0][lane * 4] = v0;
      *(v4f*)&ring[1][lane * 4] = v1;
      vbuf = xb4[2 * 64 + lane];
    }
    __syncthreads();
    for (int k = 0; k < 128; ++k) {
      // stage granule k+2 from the register loaded LAST iteration (the
      // vmcnt wait here is for a load issued a full granule ago: hidden)
      if (k + 2 < 128) *(v4f*)&ring[(k + 2) & 3][lane * 4] = vbuf;
      if (k + 3 < 128) vbuf = xb4[(k + 3) * 64 + lane];
      // flush granule k-1's checkpoints (visible since barrier k-1)
      if (k >= 1) {
        const int p = (k - 1) & 1;
        const int r0 = 2 * (k - 1);
        cs[(long)r0 * kN + lane] = mail_s[p][0][lane];
        cs[(long)(r0 + 1) * kN + lane] = mail_s[p][1][lane];
        if (lane == 0) {
          cm[r0] = mail_m[p][0];
          cm[r0 + 1] = mail_m[p][1];
        }
      }
      __syncthreads();
    }
    // epilogue: flush granule 127's checkpoints (rows 254, 255)
    cs[(long)254 * kN + lane] = mail_s[1][0][lane];
    cs[(long)255 * kN + lane] = mail_s[1][1][lane];
    if (lane == 0) {
      cm[254] = mail_m[1][0];
      cm[255] = mail_m[1][1];
    }
  }
}

// ---------------------------------------------------------------------------
// Pass 2: replay + dense coalesced write. One wave per (b,row); lane = n.
// Bit-identical replay from checkpoint; ovt[n][h] transposed staging with
// 16B-aligned rows (stride 132 floats): ds_write_b128 every 4 steps,
// ds_read_b128 in the flush. Plain stores (no nontemporal) this round.
// spike = ov > 0 (spiking requires s > th >= 0) — proven bit-exact R5..R7.
// ---------------------------------------------------------------------------
__global__ __launch_bounds__(64) void lif_pass2_kernel(
    const float* __restrict__ x, const float* __restrict__ thresh,
    const float* __restrict__ ckpt_s,
    const unsigned long long* __restrict__ ckpt_m, float* __restrict__ out) {
  const int wid = blockIdx.x;
  const int b = wid >> 8;
  const int srow = wid & 255;
  const int lane = threadIdx.x;

  __shared__ alignas(16) float ovt[kN][132];  // 33 KB, rows 528 B (16B mult)

  const v4f* __restrict__ xr4 =
      (const v4f*)(x + (long)b * kT + srow * kH) + opaque_vgpr_zero();

  v4f xb[32];
#pragma unroll
  for (int i = 0; i < 32; ++i) xb[i] = xr4[i];  // 32 loads in flight

  const float th = thresh[lane];
  float s = ckpt_s[((long)b * kS + srow) * kN + lane];
  bool prev = (ckpt_m[b * kS + srow] >> lane) & 1ULL;

#pragma unroll
  for (int q = 0; q < 32; ++q) {
    v4f o;
#pragma unroll
    for (int j = 0; j < 4; ++j) {
      const float xt = xb[q][j];
      const float u = s + xt;
      s = prev ? xt : u;  // bit-identical replay
      prev = s > th;
      o[j] = prev ? s : 0.0f;
    }
    *(v4f*)&ovt[lane][q * 4] = o;  // ds_write_b128
  }
  __syncthreads();

  float* __restrict__ obase = out + (long)b * kPerB + (long)srow * (kN * kH);
  float* __restrict__ sbase = obase + (long)kB * kPerB;
  const int h0 = (lane & 31) * 4;
  const int nh = lane >> 5;
#pragma unroll
  for (int i = 0; i < 32; ++i) {
    const int n = 2 * i + nh;
    const v4f o = *(const v4f*)&ovt[n][h0];  // ds_read_b128
    v4f sp;
#pragma unroll
    for (int j = 0; j < 4; ++j) sp[j] = o[j] > 0.0f ? 1.0f : 0.0f;
    *(v4f*)(obase + n * kH + h0) = o;   // contiguous 1 KB per wave instr
    *(v4f*)(sbase + n * kH + h0) = sp;  // contiguous 1 KB per wave instr
  }
}

// ---------------------------------------------------------------------------
// Fallback (ws too small): R4's passing fused kernel.
// ---------------------------------------------------------------------------
__global__ __launch_bounds__(128) void lif_fused_kernel(
    const float* __restrict__ x, const float* __restrict__ thresh,
    const float* __restrict__ acc0, float* __restrict__ out) {
  const int bid = blockIdx.x;
  const int b = bid >> 2;
  const int ng = bid & 3;
  const int tid = threadIdx.x;
  const int wave = tid >> 6;
  const int lane = tid & 63;
  __shared__ float buf[2][kH][64];
  const float* __restrict__ xb = x + (long)b * kT;
  float* __restrict__ outs_g = out + (long)b * kPerB + (long)(ng * 16) * kH;
  float* __restrict__ spks_g = outs_g + (long)kB * kPerB;
  if (wave == 0) {
    const int n = lane & 15;
    const float th = thresh[ng * 16 + n];
    float s = acc0[b * kN + ng * 16 + n];
    bool prev = false;
    for (int r = 0; r < kS + 1; ++r) {
      if (r < kS) {
        float* __restrict__ bk = &buf[r & 1][0][lane];
        const float* __restrict__ xr = xb + r * kH;
#pragma unroll
        for (int k = 0; k < kH; ++k) {
          const float xt = xr[k];
          const float u = s + xt;
          s = prev ? xt : u;
          prev = s > th;
          bk[k * 64] = s;
        }
      }
      __syncthreads();
    }
  } else {
    const int n = lane >> 2;
    const int hg = lane & 3;
    const float th = thresh[ng * 16 + n];
    for (int r = 0; r < kS + 1; ++r) {
      if (r > 0) {
        const int rr = r - 1;
        const float(*bk)[64] = buf[rr & 1];
        float* __restrict__ orow = outs_g + (long)rr * (kN * kH) + n * kH;
        float* __restrict__ srow = spks_g + (long)rr * (kN * kH) + n * kH;
#pragma unroll
        for (int i = 0; i < 8; ++i) {
          const int hh = hg * 4 + i * 16;
          v4f ovv, sv;
#pragma unroll
          for (int j = 0; j < 4; ++j) {
            const float v = bk[hh + j][n];
            const bool sp = v > th;
            ovv[j] = sp ? v : 0.0f;
            sv[j] = sp ? 1.0f : 0.0f;
          }
          *(v4f*)(orow + hh) = ovv;
          *(v4f*)(srow + hh) = sv;
        }
      }
      __syncthreads();
    }
  }
}

// ---------------------------------------------------------------------------
extern "C" void kernel_launch(void* const* d_in, const int* in_sizes, int n_in,
                              void* d_out, int out_size, void* d_ws, size_t ws_size,
                              hipStream_t stream) {
  const float* inputs = (const float*)d_in[0];    // [B,S,H] fp32
  const float* threshes = (const float*)d_in[1];  // [N] fp32
  const float* acc0 = (const float*)d_in[2];      // [B,N] fp32
  float* out = (float*)d_out;

  if (ws_size >= kWsS + kWsM) {
    float* ckpt_s = (float*)d_ws;
    unsigned long long* ckpt_m = (unsigned long long*)((char*)d_ws + kWsS);
    lif_pass1_kernel<<<kB, 128, 0, stream>>>(inputs, threshes, acc0, ckpt_s,
                                             ckpt_m);
    lif_pass2_kernel<<<kB * kS, kN, 0, stream>>>(inputs, threshes, ckpt_s,
                                                 ckpt_m, out);
  } else {
    lif_fused_kernel<<<kB * 4, 128, 0, stream>>>(inputs, threshes, acc0, out);
  }
}